// Round 1
// baseline (918.876 us; speedup 1.0000x reference)
//
#include <hip/hip_runtime.h>
#include <cstdint>

#define NN 20000
#define TT 256
#define EE 320000
#define GG 64
#define EMBD 768
#define FIND 512

typedef __bf16 bf16x8 __attribute__((ext_vector_type(8)));
typedef float f32x4 __attribute__((ext_vector_type(4)));

__device__ __forceinline__ float b2f(unsigned short u) {
  union { unsigned int i; float f; } v; v.i = ((unsigned int)u) << 16; return v.f;
}
__device__ __forceinline__ unsigned short f2bf(float f) {
  union { float f; unsigned int i; } v; v.f = f;
  unsigned int u = v.i;
  return (unsigned short)((u + 0x7FFFu + ((u >> 16) & 1u)) >> 16);
}

// async global->LDS, 16B per lane. LDS dest is wave-uniform base + lane*16.
__device__ __forceinline__ void gload_lds16(const void* g, void* l) {
  auto gp = reinterpret_cast<const __attribute__((address_space(1))) char*>(
      reinterpret_cast<uintptr_t>(g));
  auto lp = reinterpret_cast<__attribute__((address_space(3))) char*>(
      (unsigned int)(reinterpret_cast<uintptr_t>(l)));
  __builtin_amdgcn_global_load_lds(gp, lp, 16, 0, 0);
}

// ---------------- fused temporal conv stack: x(N,256) -> h0 bf16 (N,512) ----
__global__ __launch_bounds__(256) void k_conv(
    const float* __restrict__ x,
    const float* __restrict__ w0, const float* __restrict__ g0,
    const float* __restrict__ be0, const float* __restrict__ mu0,
    const float* __restrict__ va0,
    const float* __restrict__ w1, const float* __restrict__ w2,
    const float* __restrict__ g2, const float* __restrict__ be2,
    const float* __restrict__ mu2, const float* __restrict__ va2,
    unsigned short* __restrict__ out) {
  __shared__ float xs[288];          // t = -16..271 at idx t+16
  __shared__ float h0s[276 * 9];     // rows t=-10..265 at idx t+10, stride 9 (bank-conflict pad)
  __shared__ float w0s[264], w1s[168], w2s[128];
  __shared__ float s0[8], o0[8], s2[16], o2[16];
  const int tid = threadIdx.x;
  const int n = blockIdx.x;

  for (int i = tid; i < 264; i += 256) w0s[i] = w0[i];
  for (int i = tid; i < 168; i += 256) w1s[i] = w1[i];
  for (int i = tid; i < 128; i += 256) w2s[i] = w2[i];
  if (tid < 8)  { float s = g0[tid] * rsqrtf(va0[tid] + 1e-5f); s0[tid] = s; o0[tid] = be0[tid] - mu0[tid] * s; }
  if (tid >= 32 && tid < 48) { int j = tid - 32; float s = g2[j] * rsqrtf(va2[j] + 1e-5f); s2[j] = s; o2[j] = be2[j] - mu2[j] * s; }
  xs[tid + 16] = x[(size_t)n * TT + tid];
  if (tid >= 64 && tid < 80) { xs[tid - 64] = 0.f; xs[272 + tid - 64] = 0.f; }
  if (tid >= 128 && tid < 138) {
    int r = tid - 128;
    #pragma unroll
    for (int c = 0; c < 8; ++c) { h0s[r * 9 + c] = 0.f; h0s[(266 + r) * 9 + c] = 0.f; }
  }
  __syncthreads();

  // conv0 (k=33, 1->8) + bn0
  float c0[8] = {0.f, 0.f, 0.f, 0.f, 0.f, 0.f, 0.f, 0.f};
  for (int w = 0; w < 33; ++w) {
    float xv = xs[tid + w];
    #pragma unroll
    for (int c = 0; c < 8; ++c) c0[c] += xv * w0s[w * 8 + c];
  }
  #pragma unroll
  for (int c = 0; c < 8; ++c) h0s[(tid + 10) * 9 + c] = c0[c] * s0[c] + o0[c];
  __syncthreads();

  // conv1 depthwise (k=21) + relu
  float d[8];
  #pragma unroll
  for (int c = 0; c < 8; ++c) {
    float a = 0.f;
    for (int w = 0; w < 21; ++w) a += h0s[(tid + w) * 9 + c] * w1s[w * 8 + c];
    d[c] = fmaxf(a, 0.f);
  }
  // conv2 pointwise (8->16) + bn2 + relu
  float p[16];
  #pragma unroll
  for (int j = 0; j < 16; ++j) p[j] = 0.f;
  #pragma unroll
  for (int c = 0; c < 8; ++c) {
    float dc = d[c];
    #pragma unroll
    for (int j = 0; j < 16; ++j) p[j] += dc * w2s[c * 16 + j];
  }
  #pragma unroll
  for (int j = 0; j < 16; ++j) p[j] = fmaxf(p[j] * s2[j] + o2[j], 0.f);

  // mean-pool over 8 consecutive t (lanes within wave, 8-aligned groups)
  #pragma unroll
  for (int j = 0; j < 16; ++j) {
    float v = p[j];
    v += __shfl_xor(v, 1);
    v += __shfl_xor(v, 2);
    v += __shfl_xor(v, 4);
    p[j] = v * 0.125f;
  }
  if ((tid & 7) == 0) {
    int grp = tid >> 3;  // 0..31
    unsigned short* op = out + (size_t)n * FIND + grp * 16;
    #pragma unroll
    for (int j = 0; j < 16; ++j) op[j] = f2bf(p[j]);
  }
}

// ---------------- CSR build -------------------------------------------------
__global__ void k_count(const int* __restrict__ ei, int* __restrict__ deg) {
  int e = blockIdx.x * 256 + threadIdx.x;
  if (e < EE) atomicAdd(&deg[ei[EE + e]], 1);
}

__global__ __launch_bounds__(1024) void k_scan(const int* __restrict__ deg,
                                               int* __restrict__ row_ptr,
                                               int* __restrict__ cursor, int n) {
  __shared__ int s[1024];
  __shared__ int carry_s;
  int tid = threadIdx.x;
  if (tid == 0) carry_s = 0;
  __syncthreads();
  for (int base = 0; base < n; base += 1024) {
    int v = (base + tid < n) ? deg[base + tid] : 0;
    s[tid] = v;
    __syncthreads();
    for (int off = 1; off < 1024; off <<= 1) {
      int t = (tid >= off) ? s[tid - off] : 0;
      __syncthreads();
      s[tid] += t;
      __syncthreads();
    }
    int excl = carry_s + s[tid] - v;
    if (base + tid < n) { row_ptr[base + tid] = excl; cursor[base + tid] = excl; }
    __syncthreads();
    if (tid == 1023) carry_s = carry_s + s[1023];
    __syncthreads();
  }
  if (tid == 0) row_ptr[n] = carry_s;
}

__global__ void k_scatter(const int* __restrict__ ei, int* __restrict__ cursor,
                          int* __restrict__ csr_src) {
  int e = blockIdx.x * 256 + threadIdx.x;
  if (e < EE) {
    int d = ei[EE + e];
    int pos = atomicAdd(&cursor[d], 1);
    csr_src[pos] = ei[e];
  }
}

// ---------------- weight transpose+convert: w(K,Nc) f32 -> wt(Nc,K) bf16 ----
__global__ void k_trans(const float* __restrict__ w, unsigned short* __restrict__ wt,
                        int K, int Nc) {
  int i = blockIdx.x * 256 + threadIdx.x;
  if (i >= K * Nc) return;
  int nrow = i / K, k = i - nrow * K;
  wt[i] = f2bf(w[(size_t)k * Nc + nrow]);
}

// ---------------- aggregation: out[n] = h[n] + sum_{e in(n)} h[src[e]] ------
template <int KK>
__global__ __launch_bounds__(64) void k_agg(const unsigned short* __restrict__ h,
                                            const int* __restrict__ rp,
                                            const int* __restrict__ csr,
                                            unsigned short* __restrict__ out) {
  constexpr int NG = KK / 256;  // ushort4 groups per thread
  int node = blockIdx.x;
  int lane = threadIdx.x;
  float acc[NG * 4];
  const unsigned short* hp = h + (size_t)node * KK + lane * 4;
  #pragma unroll
  for (int g = 0; g < NG; ++g) {
    ushort4 v = *(const ushort4*)(hp + g * 256);
    acc[g * 4 + 0] = b2f(v.x); acc[g * 4 + 1] = b2f(v.y);
    acc[g * 4 + 2] = b2f(v.z); acc[g * 4 + 3] = b2f(v.w);
  }
  int s = rp[node], e = rp[node + 1];
  for (int i = s; i < e; ++i) {
    const unsigned short* sp = h + (size_t)csr[i] * KK + lane * 4;
    #pragma unroll
    for (int g = 0; g < NG; ++g) {
      ushort4 v = *(const ushort4*)(sp + g * 256);
      acc[g * 4 + 0] += b2f(v.x); acc[g * 4 + 1] += b2f(v.y);
      acc[g * 4 + 2] += b2f(v.z); acc[g * 4 + 3] += b2f(v.w);
    }
  }
  unsigned short* op = out + (size_t)node * KK + lane * 4;
  #pragma unroll
  for (int g = 0; g < NG; ++g) {
    ushort4 v;
    v.x = f2bf(acc[g * 4 + 0]); v.y = f2bf(acc[g * 4 + 1]);
    v.z = f2bf(acc[g * 4 + 2]); v.w = f2bf(acc[g * 4 + 3]);
    *(ushort4*)(op + g * 256) = v;
  }
}

// ---------------- GEMM: C(M,Nn) = relu(A(M,K) @ Bt(Nn,K)^T + bias) ----------
// A,Bt,C bf16 row-major. Nn multiple of 128, K multiple of 32.
__global__ __launch_bounds__(256) void k_gemm(const unsigned short* __restrict__ A,
                                              const unsigned short* __restrict__ Bt,
                                              const float* __restrict__ bias,
                                              unsigned short* __restrict__ C,
                                              int M, int K, int Nn) {
  __shared__ __align__(16) unsigned short As[128 * 32];
  __shared__ __align__(16) unsigned short Bs[128 * 32];
  const int tid = threadIdx.x;
  const int wave = tid >> 6, lane = tid & 63;
  const int m0 = blockIdx.y * 128;
  const int n0 = blockIdx.x * 128;
  const int wr = wave & 1, wc = wave >> 1;
  const int frag_m_row = wr * 64 + (lane & 15);
  const int frag_n_row = wc * 64 + (lane & 15);
  const int frag_kb = (lane >> 4) * 16;  // byte offset within 64B row

  f32x4 zero = {0.f, 0.f, 0.f, 0.f};
  f32x4 acc[4][4];
  #pragma unroll
  for (int mt = 0; mt < 4; ++mt)
    #pragma unroll
    for (int nt = 0; nt < 4; ++nt) acc[mt][nt] = zero;

  for (int k0 = 0; k0 < K; k0 += 32) {
    __syncthreads();
    #pragma unroll
    for (int j = 0; j < 2; ++j) {
      int chunk = (wave * 2 + j) * 64 + lane;      // 0..511
      int row = chunk >> 2, kc = chunk & 3;
      int gm = m0 + row; if (gm >= M) gm = 0;      // clamp: data unused
      gload_lds16(A + (size_t)gm * K + k0 + kc * 8, (char*)As + chunk * 16);
    }
    #pragma unroll
    for (int j = 0; j < 2; ++j) {
      int chunk = (wave * 2 + j) * 64 + lane;
      int row = chunk >> 2, kc = chunk & 3;
      gload_lds16(Bt + (size_t)(n0 + row) * K + k0 + kc * 8, (char*)Bs + chunk * 16);
    }
    __syncthreads();
    bf16x8 af[4], bfr[4];
    #pragma unroll
    for (int mt = 0; mt < 4; ++mt)
      af[mt] = *(const bf16x8*)((const char*)As + (frag_m_row + mt * 16) * 64 + frag_kb);
    #pragma unroll
    for (int nt = 0; nt < 4; ++nt)
      bfr[nt] = *(const bf16x8*)((const char*)Bs + (frag_n_row + nt * 16) * 64 + frag_kb);
    #pragma unroll
    for (int mt = 0; mt < 4; ++mt)
      #pragma unroll
      for (int nt = 0; nt < 4; ++nt)
        acc[mt][nt] = __builtin_amdgcn_mfma_f32_16x16x32_bf16(af[mt], bfr[nt], acc[mt][nt], 0, 0, 0);
  }

  const int q = lane >> 4, ccol = lane & 15;
  #pragma unroll
  for (int nt = 0; nt < 4; ++nt) {
    int n = n0 + wc * 64 + nt * 16 + ccol;
    float bv = bias[n];
    #pragma unroll
    for (int mt = 0; mt < 4; ++mt) {
      int mbase = m0 + wr * 64 + mt * 16 + q * 4;
      #pragma unroll
      for (int r = 0; r < 4; ++r) {
        int m = mbase + r;
        if (m < M) {
          float v = acc[mt][nt][r] + bv;
          v = v > 0.f ? v : 0.f;
          C[(size_t)m * Nn + n] = f2bf(v);
        }
      }
    }
  }
}

// ---------------- per-graph mean pool + dense + log_softmax -----------------
__device__ __forceinline__ int lower_bound_i(const int* arr, int n, int val) {
  int lo = 0, hi = n;
  while (lo < hi) { int mid = (lo + hi) >> 1; if (arr[mid] < val) lo = mid + 1; else hi = mid; }
  return lo;
}

__global__ __launch_bounds__(256) void k_pool(const unsigned short* __restrict__ h,
                                              const int* __restrict__ batch,
                                              const float* __restrict__ dw,
                                              const float* __restrict__ db,
                                              float* __restrict__ outp) {
  __shared__ float pl[EMBD];
  __shared__ float red[4];
  __shared__ int lohi[2];
  int g = blockIdx.x, tid = threadIdx.x;
  if (tid == 0) { lohi[0] = lower_bound_i(batch, NN, g); lohi[1] = lower_bound_i(batch, NN, g + 1); }
  if (tid < 4) red[tid] = 0.f;
  __syncthreads();
  int lo = lohi[0], hi = lohi[1];
  float a0 = 0.f, a1 = 0.f, a2 = 0.f;
  for (int n = lo; n < hi; ++n) {
    const unsigned short* hp = h + (size_t)n * EMBD;
    a0 += b2f(hp[tid]); a1 += b2f(hp[tid + 256]); a2 += b2f(hp[tid + 512]);
  }
  float inv = 1.f / fmaxf((float)(hi - lo), 1.f);
  pl[tid] = a0 * inv; pl[tid + 256] = a1 * inv; pl[tid + 512] = a2 * inv;
  __syncthreads();
  float po[4] = {0.f, 0.f, 0.f, 0.f};
  for (int f = tid; f < EMBD; f += 256) {
    float pv = pl[f];
    #pragma unroll
    for (int o = 0; o < 4; ++o) po[o] += pv * dw[f * 4 + o];
  }
  #pragma unroll
  for (int o = 0; o < 4; ++o) {
    float v = po[o];
    for (int s = 1; s < 64; s <<= 1) v += __shfl_xor(v, s);
    if ((tid & 63) == 0) atomicAdd(&red[o], v);
  }
  __syncthreads();
  if (tid == 0) {
    float l[4], m = -1e30f;
    #pragma unroll
    for (int o = 0; o < 4; ++o) { l[o] = red[o] + db[o]; m = fmaxf(m, l[o]); }
    float sum = 0.f;
    #pragma unroll
    for (int o = 0; o < 4; ++o) sum += expf(l[o] - m);
    float lse = m + logf(sum);
    #pragma unroll
    for (int o = 0; o < 4; ++o) outp[g * 4 + o] = l[o] - lse;
  }
}

// ---------------- launch ----------------------------------------------------
extern "C" void kernel_launch(void* const* d_in, const int* in_sizes, int n_in,
                              void* d_out, int out_size, void* d_ws, size_t ws_size,
                              hipStream_t stream) {
  const float* x        = (const float*)d_in[0];
  const int*   ei       = (const int*)d_in[1];
  const int*   batch    = (const int*)d_in[2];
  const float* conv0_w  = (const float*)d_in[3];
  const float* bn0_g    = (const float*)d_in[4];
  const float* bn0_b    = (const float*)d_in[5];
  const float* bn0_m    = (const float*)d_in[6];
  const float* bn0_v    = (const float*)d_in[7];
  const float* conv1_w  = (const float*)d_in[8];
  const float* conv2_w  = (const float*)d_in[9];
  const float* bn2_g    = (const float*)d_in[10];
  const float* bn2_b    = (const float*)d_in[11];
  const float* bn2_m    = (const float*)d_in[12];
  const float* bn2_v    = (const float*)d_in[13];
  const float* g1w1 = (const float*)d_in[14];
  const float* g1b1 = (const float*)d_in[15];
  const float* g1w2 = (const float*)d_in[16];
  const float* g1b2 = (const float*)d_in[17];
  const float* g2w1 = (const float*)d_in[18];
  const float* g2b1 = (const float*)d_in[19];
  const float* g2w2 = (const float*)d_in[20];
  const float* g2b2 = (const float*)d_in[21];
  const float* dw   = (const float*)d_in[22];
  const float* db   = (const float*)d_in[23];

  char* base = (char*)d_ws;
  // buffer plan (bf16):
  //   [0, 20.48M)   h0 (N*512)      -- dead after agg1; a2 (N*768) reuses [0, 30.72M)
  //   [20.48M, 40.96M) a1 (N*512)   -- dead after gemm1
  //   [40.96M, 71.68M) z  (N*768)
  //   [71.68M, 102.4M) h1 (N*768)   -- h2 reuses same region after agg2
  unsigned short* h0 = (unsigned short*)(base);
  unsigned short* a2 = (unsigned short*)(base);
  unsigned short* a1 = (unsigned short*)(base + 20480000ull);
  unsigned short* z  = (unsigned short*)(base + 40960000ull);
  unsigned short* h1 = (unsigned short*)(base + 71680000ull);
  unsigned short* h2 = h1;
  size_t off = 102400000ull;
  unsigned short* w1T = (unsigned short*)(base + off); off += 786432ull;    // 768x512
  unsigned short* w2T = (unsigned short*)(base + off); off += 1179648ull;   // 768x768
  unsigned short* w3T = (unsigned short*)(base + off); off += 1179648ull;
  unsigned short* w4T = (unsigned short*)(base + off); off += 1179648ull;
  int* deg     = (int*)(base + off); off += 80128ull;
  int* row_ptr = (int*)(base + off); off += 80128ull;
  int* cursor  = (int*)(base + off); off += 80128ull;
  int* csr_src = (int*)(base + off); off += 1280000ull;

  hipMemsetAsync(deg, 0, NN * sizeof(int), stream);

  k_conv<<<NN, 256, 0, stream>>>(x, conv0_w, bn0_g, bn0_b, bn0_m, bn0_v,
                                 conv1_w, conv2_w, bn2_g, bn2_b, bn2_m, bn2_v, h0);

  k_count<<<(EE + 255) / 256, 256, 0, stream>>>(ei, deg);
  k_scan<<<1, 1024, 0, stream>>>(deg, row_ptr, cursor, NN);
  k_scatter<<<(EE + 255) / 256, 256, 0, stream>>>(ei, cursor, csr_src);

  k_trans<<<(768 * 512 + 255) / 256, 256, 0, stream>>>(g1w1, w1T, 512, 768);
  k_trans<<<(768 * 768 + 255) / 256, 256, 0, stream>>>(g1w2, w2T, 768, 768);
  k_trans<<<(768 * 768 + 255) / 256, 256, 0, stream>>>(g2w1, w3T, 768, 768);
  k_trans<<<(768 * 768 + 255) / 256, 256, 0, stream>>>(g2w2, w4T, 768, 768);

  dim3 ggrid(6, 157);

  // GIN1
  k_agg<512><<<NN, 64, 0, stream>>>(h0, row_ptr, csr_src, a1);
  k_gemm<<<ggrid, 256, 0, stream>>>(a1, w1T, g1b1, z, NN, 512, 768);
  k_gemm<<<ggrid, 256, 0, stream>>>(z, w2T, g1b2, h1, NN, 768, 768);
  // GIN2
  k_agg<768><<<NN, 64, 0, stream>>>(h1, row_ptr, csr_src, a2);
  k_gemm<<<ggrid, 256, 0, stream>>>(a2, w3T, g2b1, z, NN, 768, 768);
  k_gemm<<<ggrid, 256, 0, stream>>>(z, w4T, g2b2, h2, NN, 768, 768);

  k_pool<<<GG, 256, 0, stream>>>(h2, batch, dw, db, (float*)d_out);
}

// Round 2
// 819.064 us; speedup vs baseline: 1.1219x; 1.1219x over previous
//
#include <hip/hip_runtime.h>
#include <cstdint>

#define NN 20000
#define TT 256
#define EE 320000
#define GG 64
#define EMBD 768
#define FIND 512

typedef __bf16 bf16x8 __attribute__((ext_vector_type(8)));
typedef float f32x4 __attribute__((ext_vector_type(4)));

__device__ __forceinline__ float b2f(unsigned short u) {
  union { unsigned int i; float f; } v; v.i = ((unsigned int)u) << 16; return v.f;
}
__device__ __forceinline__ unsigned short f2bf(float f) {
  union { float f; unsigned int i; } v; v.f = f;
  unsigned int u = v.i;
  return (unsigned short)((u + 0x7FFFu + ((u >> 16) & 1u)) >> 16);
}

// async global->LDS, 16B per lane. LDS dest is wave-uniform base + lane*16.
__device__ __forceinline__ void gload_lds16(const void* g, void* l) {
  auto gp = reinterpret_cast<const __attribute__((address_space(1))) char*>(
      reinterpret_cast<uintptr_t>(g));
  auto lp = reinterpret_cast<__attribute__((address_space(3))) char*>(
      (unsigned int)(reinterpret_cast<uintptr_t>(l)));
  __builtin_amdgcn_global_load_lds(gp, lp, 16, 0, 0);
}

// ---------------- fused temporal conv stack: x(N,256) -> h0 bf16 (N,512) ----
// 1 wave = 1 node, 4 nodes/block. Each thread handles 4 consecutive t.
// Weights read via uniform scalar loads (s_load) -- zero LDS-pipe cost.
// All lane-varying LDS traffic is aligned b128, conflict-free.
__global__ __launch_bounds__(256, 3) void k_conv(
    const float* __restrict__ x,
    const float* __restrict__ w0, const float* __restrict__ g0,
    const float* __restrict__ be0, const float* __restrict__ mu0,
    const float* __restrict__ va0,
    const float* __restrict__ w1, const float* __restrict__ w2,
    const float* __restrict__ g2, const float* __restrict__ be2,
    const float* __restrict__ mu2, const float* __restrict__ va2,
    unsigned short* __restrict__ out) {
  __shared__ float xs[4][288];        // idx = t + 16, t in [-16, 271]
  __shared__ float h0s[4][8][288];    // [node][ch][t + 12], t in [-12, 275]
  const int tid = threadIdx.x;
  const int wv = tid >> 6;            // node slot within block
  const int l = tid & 63;             // lane; handles t = 4l .. 4l+3
  const int n = blockIdx.x * 4 + wv;

  // stage x + zero halos
  float4 xv4 = *(const float4*)(x + (size_t)n * TT + 4 * l);
  *(float4*)&xs[wv][16 + 4 * l] = xv4;
  float4 z4 = make_float4(0.f, 0.f, 0.f, 0.f);
  if (l < 4) *(float4*)&xs[wv][4 * l] = z4;
  else if (l < 8) *(float4*)&xs[wv][272 + 4 * (l - 4)] = z4;
  __syncthreads();

  // conv0 (k=33, 1->8): window floats [4l, 4l+35]
  float win[36];
  #pragma unroll
  for (int i = 0; i < 9; ++i)
    *(float4*)&win[4 * i] = *(const float4*)&xs[wv][4 * l + 4 * i];
  float c0[4][8];
  #pragma unroll
  for (int j = 0; j < 4; ++j)
    #pragma unroll
    for (int c = 0; c < 8; ++c) c0[j][c] = 0.f;
  #pragma unroll
  for (int w = 0; w < 33; ++w) {
    #pragma unroll
    for (int c = 0; c < 8; ++c) {
      float wt = w0[w * 8 + c];            // uniform -> s_load
      #pragma unroll
      for (int j = 0; j < 4; ++j) c0[j][c] += win[w + j] * wt;
    }
  }
  // bn0 + store to channel-major LDS
  #pragma unroll
  for (int c = 0; c < 8; ++c) {
    float s = g0[c] * rsqrtf(va0[c] + 1e-5f);
    float o = be0[c] - mu0[c] * s;
    float4 v;
    v.x = c0[0][c] * s + o; v.y = c0[1][c] * s + o;
    v.z = c0[2][c] * s + o; v.w = c0[3][c] * s + o;
    *(float4*)&h0s[wv][c][12 + 4 * l] = v;
  }
  // zero halos of h0 rows: idx [0,12) and [268,288)
  if (l < 3) {
    #pragma unroll
    for (int c = 0; c < 8; ++c) *(float4*)&h0s[wv][c][4 * l] = z4;
  } else if (l < 8) {
    #pragma unroll
    for (int c = 0; c < 8; ++c) *(float4*)&h0s[wv][c][268 + 4 * (l - 3)] = z4;
  }
  __syncthreads();

  // conv1 depthwise (k=21) + relu, then conv2 pointwise (8->16)
  float p[4][16];
  #pragma unroll
  for (int j = 0; j < 4; ++j)
    #pragma unroll
    for (int k = 0; k < 16; ++k) p[j][k] = 0.f;
  #pragma unroll
  for (int c = 0; c < 8; ++c) {
    float hw[28];  // floats [4l, 4l+27] = t' in [4l-12, 4l+15]
    #pragma unroll
    for (int i = 0; i < 7; ++i)
      *(float4*)&hw[4 * i] = *(const float4*)&h0s[wv][c][4 * l + 4 * i];
    float d[4];
    #pragma unroll
    for (int j = 0; j < 4; ++j) {
      float a = 0.f;
      #pragma unroll
      for (int w = 0; w < 21; ++w) a += hw[j + w + 2] * w1[w * 8 + c];
      d[j] = fmaxf(a, 0.f);
    }
    #pragma unroll
    for (int k = 0; k < 16; ++k) {
      float wt = w2[c * 16 + k];
      #pragma unroll
      for (int j = 0; j < 4; ++j) p[j][k] += d[j] * wt;
    }
  }
  // bn2 + relu + mean-pool over 8 t (4 in-thread + lane pair)
  #pragma unroll
  for (int k = 0; k < 16; ++k) {
    float s = g2[k] * rsqrtf(va2[k] + 1e-5f);
    float o = be2[k] - mu2[k] * s;
    float v = 0.f;
    #pragma unroll
    for (int j = 0; j < 4; ++j) v += fmaxf(p[j][k] * s + o, 0.f);
    v += __shfl_xor(v, 1);
    p[0][k] = v * 0.125f;
  }
  if ((l & 1) == 0) {
    int grp = l >> 1;  // pool group 0..31
    unsigned short* op = out + (size_t)n * FIND + grp * 16;
    #pragma unroll
    for (int q = 0; q < 4; ++q) {
      ushort4 v;
      v.x = f2bf(p[0][q * 4 + 0]); v.y = f2bf(p[0][q * 4 + 1]);
      v.z = f2bf(p[0][q * 4 + 2]); v.w = f2bf(p[0][q * 4 + 3]);
      *(ushort4*)(op + q * 4) = v;
    }
  }
}

// ---------------- CSR build -------------------------------------------------
__global__ void k_count(const int* __restrict__ ei, int* __restrict__ deg) {
  int e = blockIdx.x * 256 + threadIdx.x;
  if (e < EE) atomicAdd(&deg[ei[EE + e]], 1);
}

__global__ __launch_bounds__(1024) void k_scan(const int* __restrict__ deg,
                                               int* __restrict__ row_ptr,
                                               int* __restrict__ cursor, int n) {
  __shared__ int s[1024];
  __shared__ int carry_s;
  int tid = threadIdx.x;
  if (tid == 0) carry_s = 0;
  __syncthreads();
  for (int base = 0; base < n; base += 1024) {
    int v = (base + tid < n) ? deg[base + tid] : 0;
    s[tid] = v;
    __syncthreads();
    for (int off = 1; off < 1024; off <<= 1) {
      int t = (tid >= off) ? s[tid - off] : 0;
      __syncthreads();
      s[tid] += t;
      __syncthreads();
    }
    int excl = carry_s + s[tid] - v;
    if (base + tid < n) { row_ptr[base + tid] = excl; cursor[base + tid] = excl; }
    __syncthreads();
    if (tid == 1023) carry_s = carry_s + s[1023];
    __syncthreads();
  }
  if (tid == 0) row_ptr[n] = carry_s;
}

__global__ void k_scatter(const int* __restrict__ ei, int* __restrict__ cursor,
                          int* __restrict__ csr_src) {
  int e = blockIdx.x * 256 + threadIdx.x;
  if (e < EE) {
    int d = ei[EE + e];
    int pos = atomicAdd(&cursor[d], 1);
    csr_src[pos] = ei[e];
  }
}

// ---------------- weight transpose+convert: w(K,Nc) f32 -> wt(Nc,K) bf16 ----
__global__ void k_trans(const float* __restrict__ w, unsigned short* __restrict__ wt,
                        int K, int Nc) {
  int i = blockIdx.x * 256 + threadIdx.x;
  if (i >= K * Nc) return;
  int nrow = i / K, k = i - nrow * K;
  wt[i] = f2bf(w[(size_t)k * Nc + nrow]);
}

// ---------------- aggregation: out[n] = h[n] + sum_{e in(n)} h[src[e]] ------
template <int KK>
__global__ __launch_bounds__(64) void k_agg(const unsigned short* __restrict__ h,
                                            const int* __restrict__ rp,
                                            const int* __restrict__ csr,
                                            unsigned short* __restrict__ out) {
  constexpr int NG = KK / 256;  // ushort4 groups per thread
  int node = blockIdx.x;
  int lane = threadIdx.x;
  float acc[NG * 4];
  const unsigned short* hp = h + (size_t)node * KK + lane * 4;
  #pragma unroll
  for (int g = 0; g < NG; ++g) {
    ushort4 v = *(const ushort4*)(hp + g * 256);
    acc[g * 4 + 0] = b2f(v.x); acc[g * 4 + 1] = b2f(v.y);
    acc[g * 4 + 2] = b2f(v.z); acc[g * 4 + 3] = b2f(v.w);
  }
  int s = rp[node], e = rp[node + 1];
  for (int i = s; i < e; ++i) {
    const unsigned short* sp = h + (size_t)csr[i] * KK + lane * 4;
    #pragma unroll
    for (int g = 0; g < NG; ++g) {
      ushort4 v = *(const ushort4*)(sp + g * 256);
      acc[g * 4 + 0] += b2f(v.x); acc[g * 4 + 1] += b2f(v.y);
      acc[g * 4 + 2] += b2f(v.z); acc[g * 4 + 3] += b2f(v.w);
    }
  }
  unsigned short* op = out + (size_t)node * KK + lane * 4;
  #pragma unroll
  for (int g = 0; g < NG; ++g) {
    ushort4 v;
    v.x = f2bf(acc[g * 4 + 0]); v.y = f2bf(acc[g * 4 + 1]);
    v.z = f2bf(acc[g * 4 + 2]); v.w = f2bf(acc[g * 4 + 3]);
    *(ushort4*)(op + g * 256) = v;
  }
}

// ---------------- GEMM: C(M,Nn) = relu(A(M,K) @ Bt(Nn,K)^T + bias) ----------
// A,Bt,C bf16 row-major. Nn multiple of 128, K multiple of 32.
__global__ __launch_bounds__(256) void k_gemm(const unsigned short* __restrict__ A,
                                              const unsigned short* __restrict__ Bt,
                                              const float* __restrict__ bias,
                                              unsigned short* __restrict__ C,
                                              int M, int K, int Nn) {
  __shared__ __align__(16) unsigned short As[128 * 32];
  __shared__ __align__(16) unsigned short Bs[128 * 32];
  const int tid = threadIdx.x;
  const int wave = tid >> 6, lane = tid & 63;
  const int m0 = blockIdx.y * 128;
  const int n0 = blockIdx.x * 128;
  const int wr = wave & 1, wc = wave >> 1;
  const int frag_m_row = wr * 64 + (lane & 15);
  const int frag_n_row = wc * 64 + (lane & 15);
  const int frag_kb = (lane >> 4) * 16;  // byte offset within 64B row

  f32x4 zero = {0.f, 0.f, 0.f, 0.f};
  f32x4 acc[4][4];
  #pragma unroll
  for (int mt = 0; mt < 4; ++mt)
    #pragma unroll
    for (int nt = 0; nt < 4; ++nt) acc[mt][nt] = zero;

  for (int k0 = 0; k0 < K; k0 += 32) {
    __syncthreads();
    #pragma unroll
    for (int j = 0; j < 2; ++j) {
      int chunk = (wave * 2 + j) * 64 + lane;      // 0..511
      int row = chunk >> 2, kc = chunk & 3;
      int gm = m0 + row; if (gm >= M) gm = 0;      // clamp: data unused
      gload_lds16(A + (size_t)gm * K + k0 + kc * 8, (char*)As + chunk * 16);
    }
    #pragma unroll
    for (int j = 0; j < 2; ++j) {
      int chunk = (wave * 2 + j) * 64 + lane;
      int row = chunk >> 2, kc = chunk & 3;
      gload_lds16(Bt + (size_t)(n0 + row) * K + k0 + kc * 8, (char*)Bs + chunk * 16);
    }
    __syncthreads();
    bf16x8 af[4], bfr[4];
    #pragma unroll
    for (int mt = 0; mt < 4; ++mt)
      af[mt] = *(const bf16x8*)((const char*)As + (frag_m_row + mt * 16) * 64 + frag_kb);
    #pragma unroll
    for (int nt = 0; nt < 4; ++nt)
      bfr[nt] = *(const bf16x8*)((const char*)Bs + (frag_n_row + nt * 16) * 64 + frag_kb);
    #pragma unroll
    for (int mt = 0; mt < 4; ++mt)
      #pragma unroll
      for (int nt = 0; nt < 4; ++nt)
        acc[mt][nt] = __builtin_amdgcn_mfma_f32_16x16x32_bf16(af[mt], bfr[nt], acc[mt][nt], 0, 0, 0);
  }

  const int q = lane >> 4, ccol = lane & 15;
  #pragma unroll
  for (int nt = 0; nt < 4; ++nt) {
    int n = n0 + wc * 64 + nt * 16 + ccol;
    float bv = bias[n];
    #pragma unroll
    for (int mt = 0; mt < 4; ++mt) {
      int mbase = m0 + wr * 64 + mt * 16 + q * 4;
      #pragma unroll
      for (int r = 0; r < 4; ++r) {
        int m = mbase + r;
        if (m < M) {
          float v = acc[mt][nt][r] + bv;
          v = v > 0.f ? v : 0.f;
          C[(size_t)m * Nn + n] = f2bf(v);
        }
      }
    }
  }
}

// ---------------- per-graph mean pool + dense + log_softmax -----------------
__device__ __forceinline__ int lower_bound_i(const int* arr, int n, int val) {
  int lo = 0, hi = n;
  while (lo < hi) { int mid = (lo + hi) >> 1; if (arr[mid] < val) lo = mid + 1; else hi = mid; }
  return lo;
}

__global__ __launch_bounds__(256) void k_pool(const unsigned short* __restrict__ h,
                                              const int* __restrict__ batch,
                                              const float* __restrict__ dw,
                                              const float* __restrict__ db,
                                              float* __restrict__ outp) {
  __shared__ float pl[EMBD];
  __shared__ float red[4];
  __shared__ int lohi[2];
  int g = blockIdx.x, tid = threadIdx.x;
  if (tid == 0) { lohi[0] = lower_bound_i(batch, NN, g); lohi[1] = lower_bound_i(batch, NN, g + 1); }
  if (tid < 4) red[tid] = 0.f;
  __syncthreads();
  int lo = lohi[0], hi = lohi[1];
  float a0 = 0.f, a1 = 0.f, a2 = 0.f;
  for (int n = lo; n < hi; ++n) {
    const unsigned short* hp = h + (size_t)n * EMBD;
    a0 += b2f(hp[tid]); a1 += b2f(hp[tid + 256]); a2 += b2f(hp[tid + 512]);
  }
  float inv = 1.f / fmaxf((float)(hi - lo), 1.f);
  pl[tid] = a0 * inv; pl[tid + 256] = a1 * inv; pl[tid + 512] = a2 * inv;
  __syncthreads();
  float po[4] = {0.f, 0.f, 0.f, 0.f};
  for (int f = tid; f < EMBD; f += 256) {
    float pv = pl[f];
    #pragma unroll
    for (int o = 0; o < 4; ++o) po[o] += pv * dw[f * 4 + o];
  }
  #pragma unroll
  for (int o = 0; o < 4; ++o) {
    float v = po[o];
    for (int s = 1; s < 64; s <<= 1) v += __shfl_xor(v, s);
    if ((tid & 63) == 0) atomicAdd(&red[o], v);
  }
  __syncthreads();
  if (tid == 0) {
    float l[4], m = -1e30f;
    #pragma unroll
    for (int o = 0; o < 4; ++o) { l[o] = red[o] + db[o]; m = fmaxf(m, l[o]); }
    float sum = 0.f;
    #pragma unroll
    for (int o = 0; o < 4; ++o) sum += expf(l[o] - m);
    float lse = m + logf(sum);
    #pragma unroll
    for (int o = 0; o < 4; ++o) outp[g * 4 + o] = l[o] - lse;
  }
}

// ---------------- launch ----------------------------------------------------
extern "C" void kernel_launch(void* const* d_in, const int* in_sizes, int n_in,
                              void* d_out, int out_size, void* d_ws, size_t ws_size,
                              hipStream_t stream) {
  const float* x        = (const float*)d_in[0];
  const int*   ei       = (const int*)d_in[1];
  const int*   batch    = (const int*)d_in[2];
  const float* conv0_w  = (const float*)d_in[3];
  const float* bn0_g    = (const float*)d_in[4];
  const float* bn0_b    = (const float*)d_in[5];
  const float* bn0_m    = (const float*)d_in[6];
  const float* bn0_v    = (const float*)d_in[7];
  const float* conv1_w  = (const float*)d_in[8];
  const float* conv2_w  = (const float*)d_in[9];
  const float* bn2_g    = (const float*)d_in[10];
  const float* bn2_b    = (const float*)d_in[11];
  const float* bn2_m    = (const float*)d_in[12];
  const float* bn2_v    = (const float*)d_in[13];
  const float* g1w1 = (const float*)d_in[14];
  const float* g1b1 = (const float*)d_in[15];
  const float* g1w2 = (const float*)d_in[16];
  const float* g1b2 = (const float*)d_in[17];
  const float* g2w1 = (const float*)d_in[18];
  const float* g2b1 = (const float*)d_in[19];
  const float* g2w2 = (const float*)d_in[20];
  const float* g2b2 = (const float*)d_in[21];
  const float* dw   = (const float*)d_in[22];
  const float* db   = (const float*)d_in[23];

  char* base = (char*)d_ws;
  // buffer plan (bf16):
  //   [0, 20.48M)   h0 (N*512)      -- dead after agg1; a2 (N*768) reuses [0, 30.72M)
  //   [20.48M, 40.96M) a1 (N*512)   -- dead after gemm1
  //   [40.96M, 71.68M) z  (N*768)
  //   [71.68M, 102.4M) h1 (N*768)   -- h2 reuses same region after agg2
  unsigned short* h0 = (unsigned short*)(base);
  unsigned short* a2 = (unsigned short*)(base);
  unsigned short* a1 = (unsigned short*)(base + 20480000ull);
  unsigned short* z  = (unsigned short*)(base + 40960000ull);
  unsigned short* h1 = (unsigned short*)(base + 71680000ull);
  unsigned short* h2 = h1;
  size_t off = 102400000ull;
  unsigned short* w1T = (unsigned short*)(base + off); off += 786432ull;    // 768x512
  unsigned short* w2T = (unsigned short*)(base + off); off += 1179648ull;   // 768x768
  unsigned short* w3T = (unsigned short*)(base + off); off += 1179648ull;
  unsigned short* w4T = (unsigned short*)(base + off); off += 1179648ull;
  int* deg     = (int*)(base + off); off += 80128ull;
  int* row_ptr = (int*)(base + off); off += 80128ull;
  int* cursor  = (int*)(base + off); off += 80128ull;
  int* csr_src = (int*)(base + off); off += 1280000ull;

  hipMemsetAsync(deg, 0, NN * sizeof(int), stream);

  k_conv<<<NN / 4, 256, 0, stream>>>(x, conv0_w, bn0_g, bn0_b, bn0_m, bn0_v,
                                     conv1_w, conv2_w, bn2_g, bn2_b, bn2_m, bn2_v, h0);

  k_count<<<(EE + 255) / 256, 256, 0, stream>>>(ei, deg);
  k_scan<<<1, 1024, 0, stream>>>(deg, row_ptr, cursor, NN);
  k_scatter<<<(EE + 255) / 256, 256, 0, stream>>>(ei, cursor, csr_src);

  k_trans<<<(768 * 512 + 255) / 256, 256, 0, stream>>>(g1w1, w1T, 512, 768);
  k_trans<<<(768 * 768 + 255) / 256, 256, 0, stream>>>(g1w2, w2T, 768, 768);
  k_trans<<<(768 * 768 + 255) / 256, 256, 0, stream>>>(g2w1, w3T, 768, 768);
  k_trans<<<(768 * 768 + 255) / 256, 256, 0, stream>>>(g2w2, w4T, 768, 768);

  dim3 ggrid(6, 157);

  // GIN1
  k_agg<512><<<NN, 64, 0, stream>>>(h0, row_ptr, csr_src, a1);
  k_gemm<<<ggrid, 256, 0, stream>>>(a1, w1T, g1b1, z, NN, 512, 768);
  k_gemm<<<ggrid, 256, 0, stream>>>(z, w2T, g1b2, h1, NN, 768, 768);
  // GIN2
  k_agg<768><<<NN, 64, 0, stream>>>(h1, row_ptr, csr_src, a2);
  k_gemm<<<ggrid, 256, 0, stream>>>(a2, w3T, g2b1, z, NN, 768, 768);
  k_gemm<<<ggrid, 256, 0, stream>>>(z, w4T, g2b2, h2, NN, 768, 768);

  k_pool<<<GG, 256, 0, stream>>>(h2, batch, dw, db, (float*)d_out);
}